// Round 3
// baseline (622.732 us; speedup 1.0000x reference)
//
#include <hip/hip_runtime.h>
#include <hip/hip_bf16.h>
#include <stdint.h>

static constexpr int B_  = 32;
static constexpr int E_  = 256;
static constexpr int N_  = 512;    // 2E
static constexpr int C_  = 256;    // H*F
static constexpr int BN  = B_ * N_;                      // 16384 = 2^14
static constexpr int NODE_ELEMS = B_ * N_ * C_;          // 4,194,304
static constexpr int ADJ_ELEMS  = B_ * 14 * N_ * N_;     // 117,440,512

#define LOG2E 1.44269504088896340736f

typedef __attribute__((ext_vector_type(8))) short v8bf;
typedef __attribute__((ext_vector_type(4))) float v4f;

__device__ __forceinline__ unsigned short f2bfbits(float f) {
  union { float f; unsigned u; } x; x.f = f;
  unsigned u = x.u;
  return (unsigned short)((u + 0x7FFFu + ((u >> 16) & 1u)) >> 16);
}

// ---------------- dtype-agnostic input conversion ----------------
// kind 0: float -> f32 ; kind 1: int -> i32 ; kind 2: float -> bf16 TRANSPOSED 256x256
struct ConvArgs {
  const void* src[15];
  void* dst[15];
  int n[15];
  int kind[15];
};

__global__ __launch_bounds__(256) void k_conv2(ConvArgs a, const unsigned* fprobe,
                                               const unsigned* iprobe) {
  __shared__ int fk_s, ik_s;
  int t = threadIdx.x;
  if (t == 0) {
    int c_even = 0, c_lo = 0;
    for (int k = 0; k < 32; ++k) {
      unsigned w = fprobe[2 * k];
      unsigned e32 = (w >> 23) & 0xFFu;
      unsigned elo = (w >> 7) & 0xFFu;
      if (e32 >= 105u && e32 <= 135u) ++c_even;
      if (elo >= 105u && elo <= 135u) ++c_lo;
    }
    fk_s = (c_even < 16) ? 2 : ((c_lo >= 16) ? 1 : 0);   // 2=f64, 1=bf16, 0=f32
    int hi0 = 0;
    for (int k = 0; k < 32; ++k) if (iprobe[2 * k + 1] == 0u) ++hi0;
    ik_s = (hi0 >= 30) ? 1 : 0;                          // 1=i64, 0=i32
  }
  __syncthreads();
  int fk = fk_s, ik = ik_s;
  int arr = blockIdx.y;
  int n = a.n[arr], kind = a.kind[arr];
  for (int idx = blockIdx.x * 256 + t; idx < n; idx += gridDim.x * 256) {
    if (kind == 1) {
      int v;
      if (ik == 1) v = (int)((const long long*)a.src[arr])[idx];
      else         v = ((const int*)a.src[arr])[idx];
      ((int*)a.dst[arr])[idx] = v;
    } else {
      float v;
      if (fk == 2) {
        v = (float)((const double*)a.src[arr])[idx];
      } else if (fk == 1) {
        unsigned short u = ((const unsigned short*)a.src[arr])[idx];
        union { unsigned u; float f; } c; c.u = (unsigned)u << 16; v = c.f;
      } else {
        v = ((const float*)a.src[arr])[idx];
      }
      if (kind == 0) {
        ((float*)a.dst[arr])[idx] = v;
      } else {           // kind 2: bf16, transposed [256][256]
        int kk = idx >> 8, cc = idx & 255;
        ((unsigned short*)a.dst[arr])[cc * 256 + kk] = f2bfbits(v);
      }
    }
  }
}

// ---------------- node features v4: 4 nodes per 256-thread block ----------------
__global__ __launch_bounds__(256) void k_feat4(
    const int* __restrict__ player, const float* __restrict__ Ax, const float* __restrict__ Ay,
    const float* __restrict__ Bx, const float* __restrict__ By,
    const float* __restrict__ emb, const float* __restrict__ Wc, const float* __restrict__ bc,
    const float* __restrict__ Wm, const float* __restrict__ bm, float* __restrict__ x) {
  int t = threadIdx.x, sub = t >> 6, lane = t & 63;
  int id = blockIdx.x * 4 + sub;        // b*512 + n
  int b = id >> 9, n = id & 511;
  int e = n >> 1, side = n & 1;
  __shared__ float feat[4][64];
  float v;
  if (lane < 32) {
    float cx = side ? Bx[b * E_ + e] : Ax[b * E_ + e];
    float cy = side ? By[b * E_ + e] : Ay[b * E_ + e];
    v = fmaxf(fmaf(cx, Wc[lane], fmaf(cy, Wc[32 + lane], bc[lane])), 0.f);
  } else {
    int pid = player[b * 2 + side];
    v = emb[pid * 32 + (lane - 32)];
  }
  feat[sub][lane] = v;
  __syncthreads();
  float acc = bm[lane];
  #pragma unroll 8
  for (int c = 0; c < 64; ++c) acc = fmaf(feat[sub][c], Wm[c * 64 + lane], acc);
  x[(size_t)id * 64 + lane] = acc;
}

// ---------------- layer-1 tiled GEMM (f32) + fused GAT score epilogue ----------------
// Writes h as bf16 TRANSPOSED hbT[f * 16384 + row]  (attn B-operand layout).
__global__ __launch_bounds__(256) void k_gemm(
    const float* __restrict__ x, const float* __restrict__ W, unsigned short* __restrict__ hbT,
    int K, const float* __restrict__ att, float* __restrict__ ssO, float* __restrict__ sdO) {
  __shared__ float xs[64 * 64];
  __shared__ float wt[64 * 64];
  int row0 = blockIdx.x * 64;
  int col0 = blockIdx.y * 64;
  int hd = blockIdx.y;
  int t = threadIdx.x;
  int tx = t & 15, ty = t >> 4;
  float acc[4][4] = {};
  for (int kt = 0; kt < K; kt += 64) {
    #pragma unroll
    for (int q = 0; q < 4; ++q) {
      int v = q * 256 + t;            // float4 chunk id 0..1023
      int r = v >> 4, c = (v & 15) * 4;
      *(float4*)&xs[r * 64 + c] = *(const float4*)&x[(size_t)(row0 + r) * K + kt + c];
      *(float4*)&wt[r * 64 + c] = *(const float4*)&W[(size_t)(kt + r) * C_ + col0 + c];
    }
    __syncthreads();
    #pragma unroll 4
    for (int k = 0; k < 64; ++k) {
      float xv[4];
      #pragma unroll
      for (int r = 0; r < 4; ++r) xv[r] = xs[(ty * 4 + r) * 64 + k];
      float4 wf = *(const float4*)&wt[k * 64 + tx * 4];
      #pragma unroll
      for (int r = 0; r < 4; ++r) {
        acc[r][0] = fmaf(xv[r], wf.x, acc[r][0]);
        acc[r][1] = fmaf(xv[r], wf.y, acc[r][1]);
        acc[r][2] = fmaf(xv[r], wf.z, acc[r][2]);
        acc[r][3] = fmaf(xv[r], wf.w, acc[r][3]);
      }
    }
    __syncthreads();
  }
  // bf16 transposed store: for fixed col c, acc[0..3][c] are 4 consecutive rows.
  #pragma unroll
  for (int c = 0; c < 4; ++c) {
    unsigned f = (unsigned)(col0 + tx * 4 + c);
    ushort4 o;
    o.x = f2bfbits(acc[0][c]); o.y = f2bfbits(acc[1][c]);
    o.z = f2bfbits(acc[2][c]); o.w = f2bfbits(acc[3][c]);
    *(ushort4*)&hbT[(f << 14) + row0 + ty * 4] = o;
  }
  float attS[4], attD[4];
  #pragma unroll
  for (int c = 0; c < 4; ++c) {
    attS[c] = att[hd * 128 + tx * 4 + c];
    attD[c] = att[hd * 128 + 64 + tx * 4 + c];
  }
  #pragma unroll
  for (int r = 0; r < 4; ++r) {
    float p1 = acc[r][0] * attS[0] + acc[r][1] * attS[1] + acc[r][2] * attS[2] + acc[r][3] * attS[3];
    float p2 = acc[r][0] * attD[0] + acc[r][1] * attD[1] + acc[r][2] * attD[2] + acc[r][3] * attD[3];
    #pragma unroll
    for (int d = 8; d > 0; d >>= 1) {
      p1 += __shfl_xor(p1, d, 16);
      p2 += __shfl_xor(p2, d, 16);
    }
    if (tx == 0) {
      int row = row0 + ty * 4 + r;
      int bb = row >> 9, nn = row & 511;
      int idx = (bb * 4 + hd) * N_ + nn;
      ssO[idx] = p1; sdO[idx] = p2;
    }
  }
}

// ---------------- layer-2 MFMA GEMM (bf16 in) + fused score epilogue ----------------
// Writes h as bf16 TRANSPOSED hbT[f * 16384 + row].
__global__ __launch_bounds__(256) void k_gemm2_mfma(
    const unsigned short* __restrict__ xb, const unsigned short* __restrict__ wt,
    unsigned short* __restrict__ hbT, const float* __restrict__ att,
    float* __restrict__ ssO, float* __restrict__ sdO) {
  int row0 = blockIdx.x * 64;
  int col0 = blockIdx.y * 64;
  int hd = blockIdx.y;
  int t = threadIdx.x, w = t >> 6, l = t & 63;
  int lane16 = l & 15, quad = l >> 4;
  int arow = row0 + w * 16 + lane16;        // A m-row
  v4f acc[4] = {};
  #pragma unroll
  for (int ks = 0; ks < 8; ++ks) {
    int kb = ks * 32 + quad * 8;
    v8bf a = *(const v8bf*)&xb[(size_t)arow * 256 + kb];
    #pragma unroll
    for (int fs = 0; fs < 4; ++fs) {
      v8bf b = *(const v8bf*)&wt[(size_t)(col0 + fs * 16 + lane16) * 256 + kb];
      acc[fs] = __builtin_amdgcn_mfma_f32_16x16x32_bf16(a, b, acc[fs], 0, 0, 0);
    }
  }
  // bf16 transposed store: acc[fs][0..3] = rows quad*4+0..3 (consecutive), col fixed.
  #pragma unroll
  for (int fs = 0; fs < 4; ++fs) {
    unsigned f = (unsigned)(col0 + fs * 16 + lane16);
    ushort4 o;
    o.x = f2bfbits(acc[fs][0]); o.y = f2bfbits(acc[fs][1]);
    o.z = f2bfbits(acc[fs][2]); o.w = f2bfbits(acc[fs][3]);
    *(ushort4*)&hbT[(f << 14) + row0 + w * 16 + quad * 4] = o;
  }
  float attS[4], attD[4];
  #pragma unroll
  for (int fs = 0; fs < 4; ++fs) {
    attS[fs] = att[hd * 128 + fs * 16 + lane16];
    attD[fs] = att[hd * 128 + 64 + fs * 16 + lane16];
  }
  #pragma unroll
  for (int r = 0; r < 4; ++r) {
    int row = row0 + w * 16 + quad * 4 + r;
    float p1 = acc[0][r] * attS[0] + acc[1][r] * attS[1] + acc[2][r] * attS[2] + acc[3][r] * attS[3];
    float p2 = acc[0][r] * attD[0] + acc[1][r] * attD[1] + acc[2][r] * attD[2] + acc[3][r] * attD[3];
    #pragma unroll
    for (int d = 8; d > 0; d >>= 1) {
      p1 += __shfl_xor(p1, d, 16);
      p2 += __shfl_xor(p2, d, 16);
    }
    if (lane16 == 0) {
      int bb = row >> 9, nn = row & 511;
      int idx = (bb * 4 + hd) * N_ + nn;
      ssO[idx] = p1; sdO[idx] = p2;
    }
  }
}

// ---------------- MFMA attention v4: B-fragments direct from global hbT ----------------
// No LDS h-staging, no in-loop barriers. RELU=1: bf16 out (relu); RELU=0: f32 NT out.
template <int RELU>
__global__ __launch_bounds__(256) void k_attn_mfma4(
    const unsigned short* __restrict__ hbT, const float* __restrict__ ss,
    const float* __restrict__ sd, void* __restrict__ outp) {
  __shared__ float sdl[512];
  __shared__ float red[4];
  int blk = blockIdx.x;
  int it = blk & 7, hd = (blk >> 3) & 3, b = blk >> 5;
  int i0 = it * 64, bh = b * 4 + hd;
  int t = threadIdx.x, w = t >> 6, l = t & 63;
  int lane16 = l & 15, quad = l >> 4;
  float v0 = sd[(size_t)bh * N_ + t];
  float v1 = sd[(size_t)bh * N_ + 256 + t];
  sdl[t] = v0; sdl[256 + t] = v1;
  float mx = fmaxf(v0, v1);
  #pragma unroll
  for (int d = 32; d > 0; d >>= 1) mx = fmaxf(mx, __shfl_xor(mx, d, 64));
  if (l == 0) red[w] = mx;
  __syncthreads();
  mx = fmaxf(fmaxf(red[0], red[1]), fmaxf(red[2], red[3]));
  int iw = i0 + w * 16 + lane16;           // this lane's i
  float ss_s = ss[(size_t)bh * N_ + iw];
  float sv0 = ss_s + mx;
  float m2_s = fmaxf(sv0, 0.2f * sv0) * LOG2E;  // leaky monotone -> row-max bound
  float lsum = 0.f;
  v4f acc[4] = {};
  const unsigned short* hb = hbT + ((unsigned)(hd * 64) << 14) + b * 512;
  for (int jt = 0; jt < 8; ++jt) {
    int j0 = jt * 64;
    #pragma unroll
    for (int ks = 0; ks < 2; ++ks) {
      int kb = ks * 32 + quad * 8;
      v8bf afr;
      #pragma unroll
      for (int q = 0; q < 8; ++q) {
        int j = j0 + kb + q;
        float sv = ss_s + sdl[j];
        float sc = fmaxf(sv, 0.2f * sv);
        float p = exp2f(fmaf(sc, LOG2E, -m2_s));
        if (iw == j) p = 0.f;
        lsum += p;
        afr[q] = (short)f2bfbits(p);
      }
      #pragma unroll
      for (int fs = 0; fs < 4; ++fs) {
        v8bf bfr = *(const v8bf*)&hb[((unsigned)(fs * 16 + lane16) << 14) + j0 + kb];
        acc[fs] = __builtin_amdgcn_mfma_f32_16x16x32_bf16(afr, bfr, acc[fs], 0, 0, 0);
      }
    }
  }
  // cross-quad reduce of row sums; after this every quad holds row lane16's sum.
  lsum += __shfl_xor(lsum, 16, 64);
  lsum += __shfl_xor(lsum, 32, 64);
  // epilogue: C/D layout col = lane16 (f), row = quad*4 + reg (i)
  #pragma unroll
  for (int r = 0; r < 4; ++r) {
    int i = i0 + w * 16 + quad * 4 + r;
    float scale = 1.f / __shfl(lsum, quad * 4 + r, 16);
    #pragma unroll
    for (int fs = 0; fs < 4; ++fs) {
      int f = fs * 16 + lane16;
      float vv = acc[fs][r] * scale;
      size_t o = (size_t)(b * N_ + i) * C_ + hd * 64 + f;
      if constexpr (RELU) {
        ((unsigned short*)outp)[o] = f2bfbits(fmaxf(vv, 0.f));
      } else {
        __builtin_nontemporal_store(vv, &((float*)outp)[o]);
      }
    }
  }
}

// ---------------- adjacency v3: block-uniform (plane), 8 rows/block, NT stores ----------------
__global__ __launch_bounds__(256) void k_adjf3(
    const int* __restrict__ st, float* __restrict__ adj) {
  int plane = blockIdx.y;                 // b*14 + r
  int r = plane % 14;
  int b = plane / 14;
  int i0 = blockIdx.x * 8;                // 8 rows per block
  const int* stb = st + b * 255;
  size_t base = (size_t)plane * (512 * 512);
  #pragma unroll
  for (int itr = 0; itr < 4; ++itr) {
    int lin = itr * 256 + threadIdx.x;    // 0..1023 float4-chunks within 8 rows
    int i = i0 + (lin >> 7);
    int j0 = (lin & 127) << 2;
    float vals[4];
    #pragma unroll
    for (int q = 0; q < 4; ++q) {
      int j = j0 + q;
      int d = j - i;
      int ad = d < 0 ? -d : d;
      int mn = d < 0 ? j : i;
      int m4 = mn & 3;
      float v = 0.f;
      if (r == 13) {
        bool excl = (d == 0) || (ad == 2) || (ad == 3 && m4 == 0) || (ad == 1 && m4 == 3);
        v = excl ? 0.f : 1.f;
      } else if (r == 11) {
        v = (ad == 2 && (m4 == 0 || m4 == 3)) ? 1.f : 0.f;
      } else if (r == 12) {
        v = (ad == 2 && (m4 == 1 || m4 == 2)) ? 1.f : 0.f;
      } else {
        bool sp = (ad == 3 && m4 == 0) || (ad == 1 && m4 == 3);
        if (sp) v = (stb[mn >> 1] == r) ? 1.f : 0.f;
      }
      vals[q] = v;
    }
    v4f o = { vals[0], vals[1], vals[2], vals[3] };
    __builtin_nontemporal_store(o, (v4f*)&adj[base + (size_t)i * 512 + j0]);
  }
}

// ---------------- adjacency fallback: raw input + per-block sniff ----------------
__global__ __launch_bounds__(256) void k_adjf(
    const unsigned* __restrict__ st_raw, float* __restrict__ adj) {
  __shared__ int i64_s;
  if (threadIdx.x == 0) {
    int hi0 = 0;
    for (int k = 0; k < 32; ++k) if (st_raw[2 * k + 1] == 0u) ++hi0;
    i64_s = (hi0 >= 30) ? 1 : 0;
  }
  __syncthreads();
  int is64 = i64_s;
  int chunk = blockIdx.x * 256 + threadIdx.x;
  int j0 = (chunk & 127) << 2;
  int rowid = chunk >> 7;
  int i = rowid & 511;
  int plane = rowid >> 9;
  int r = plane % 14;
  int b = plane / 14;
  float vals[4];
  #pragma unroll
  for (int q = 0; q < 4; ++q) {
    int j = j0 + q;
    int d = j - i;
    int ad = d < 0 ? -d : d;
    int mn = d < 0 ? j : i;
    int m4 = mn & 3;
    float v = 0.f;
    if (r == 13) {
      bool excl = (d == 0) || (ad == 2) || (ad == 3 && m4 == 0) || (ad == 1 && m4 == 3);
      v = excl ? 0.f : 1.f;
    } else if (r == 11) {
      v = (ad == 2 && (m4 == 0 || m4 == 3)) ? 1.f : 0.f;
    } else if (r == 12) {
      v = (ad == 2 && (m4 == 1 || m4 == 2)) ? 1.f : 0.f;
    } else {
      bool sp = (ad == 3 && m4 == 0) || (ad == 1 && m4 == 3);
      if (sp) {
        int e = b * 255 + (mn >> 1);
        int stv = is64 ? (int)st_raw[2 * e] : (int)st_raw[e];
        v = (stv == r) ? 1.f : 0.f;
      }
    }
    vals[q] = v;
  }
  *(float4*)&adj[(size_t)chunk * 4] = make_float4(vals[0], vals[1], vals[2], vals[3]);
}

// ---------------- sentinel ----------------
__global__ void k_sentinel(float* out, float v) {
  if (threadIdx.x == 0 && blockIdx.x == 0) out[0] = v;
}

extern "C" void kernel_launch(void* const* d_in, const int* in_sizes, int n_in,
                              void* d_out, int out_size, void* d_ws, size_t ws_size,
                              hipStream_t stream) {
  static const int expA[16] = {64,8160,8192,8192,8192,8192,1,1120,64,32,4096,64,16384,512,65536,512};
  static const int expB[15] = {64,8160,8192,8192,8192,8192,1120,64,32,4096,64,16384,512,65536,512};
  int mismatch = -1;
  int base = 7;
  if (n_in == 16) {
    base = 7;
    for (int i = 0; i < 16; ++i) if (in_sizes[i] != expA[i]) { mismatch = i; break; }
  } else if (n_in == 15) {
    base = 6;
    for (int i = 0; i < 15; ++i) if (in_sizes[i] != expB[i]) { mismatch = i; break; }
  } else {
    mismatch = 17;
  }
  if (mismatch < 0 && out_size != NODE_ELEMS + ADJ_ELEMS) mismatch = 16;

  float* out_node = (float*)d_out;                 // f32 output
  float* out_adjf = out_node + NODE_ELEMS;

  // Scratch carved from the f32 adj output region (470 MB); adj written last.
  char* scr = (char*)out_adjf;
  float* x  = (float*)(scr);                       //  4 MB
  unsigned short* hbT = (unsigned short*)(scr + (size_t)( 4u << 20)); // 8 MB bf16 h^T [f][row]
  unsigned short* x2b = (unsigned short*)(scr + (size_t)(24u << 20)); // 8 MB bf16
  float* ss = (float*)(scr + (size_t)(44u << 20)); // 256 KB
  float* sd = (float*)(scr + (size_t)(45u << 20)); // 256 KB
  float* cv = (float*)(scr + (size_t)(48u << 20)); // converted inputs

  float* cAx  = cv + 0;
  float* cAy  = cv + 8192;
  float* cBx  = cv + 16384;
  float* cBy  = cv + 24576;
  float* cEmb = cv + 32768;
  float* cWc  = cv + 33888;
  float* cbc  = cv + 33952;
  float* cWm  = cv + 33984;
  float* cbm  = cv + 38080;
  float* cW1  = cv + 38144;
  float* cA1  = cv + 54528;
  unsigned short* cW2T = (unsigned short*)(cv + 55040);  // 128 KB bf16 transposed
  float* cA2  = cv + 120576;
  int*   cPl  = (int*)(cv + 121088);

  bool ws_ok = (ws_size >= 8160 * sizeof(int));
  int* cSt = ws_ok ? (int*)d_ws : nullptr;

  ConvArgs a;
  a.src[0]  = d_in[2];        a.dst[0]  = cAx;  a.n[0]  = 8192;  a.kind[0]  = 0;
  a.src[1]  = d_in[3];        a.dst[1]  = cAy;  a.n[1]  = 8192;  a.kind[1]  = 0;
  a.src[2]  = d_in[4];        a.dst[2]  = cBx;  a.n[2]  = 8192;  a.kind[2]  = 0;
  a.src[3]  = d_in[5];        a.dst[3]  = cBy;  a.n[3]  = 8192;  a.kind[3]  = 0;
  a.src[4]  = d_in[base + 0]; a.dst[4]  = cEmb; a.n[4]  = 1120;  a.kind[4]  = 0;
  a.src[5]  = d_in[base + 1]; a.dst[5]  = cWc;  a.n[5]  = 64;    a.kind[5]  = 0;
  a.src[6]  = d_in[base + 2]; a.dst[6]  = cbc;  a.n[6]  = 32;    a.kind[6]  = 0;
  a.src[7]  = d_in[base + 3]; a.dst[7]  = cWm;  a.n[7]  = 4096;  a.kind[7]  = 0;
  a.src[8]  = d_in[base + 4]; a.dst[8]  = cbm;  a.n[8]  = 64;    a.kind[8]  = 0;
  a.src[9]  = d_in[base + 5]; a.dst[9]  = cW1;  a.n[9]  = 16384; a.kind[9]  = 0;
  a.src[10] = d_in[base + 6]; a.dst[10] = cA1;  a.n[10] = 512;   a.kind[10] = 0;
  a.src[11] = d_in[base + 7]; a.dst[11] = cW2T; a.n[11] = 65536; a.kind[11] = 2;
  a.src[12] = d_in[base + 8]; a.dst[12] = cA2;  a.n[12] = 512;   a.kind[12] = 0;
  a.src[13] = d_in[0];        a.dst[13] = cPl;  a.n[13] = 64;    a.kind[13] = 1;
  a.src[14] = d_in[1];        a.dst[14] = ws_ok ? (void*)cSt : (void*)cPl;
  a.n[14] = ws_ok ? 8160 : 0; a.kind[14] = 1;

  k_conv2<<<dim3(64, 15), 256, 0, stream>>>(a, (const unsigned*)d_in[base + 3],
                                            (const unsigned*)d_in[0]);

  k_feat4<<<BN / 4, 256, 0, stream>>>(cPl, cAx, cAy, cBx, cBy, cEmb, cWc, cbc, cWm, cbm, x);

  // ---- layer 1 ----
  k_gemm<<<dim3(BN / 64, 4), 256, 0, stream>>>(x, cW1, hbT, 64, cA1, ss, sd);
  k_attn_mfma4<1><<<B_ * 4 * (N_ / 64), 256, 0, stream>>>(hbT, ss, sd, x2b);

  // ---- layer 2 ----
  k_gemm2_mfma<<<dim3(BN / 64, 4), 256, 0, stream>>>(x2b, cW2T, hbT, cA2, ss, sd);
  k_attn_mfma4<0><<<B_ * 4 * (N_ / 64), 256, 0, stream>>>(hbT, ss, sd, out_node);

  // ---- adjacency last (scratch lives in its output region) ----
  if (ws_ok) {
    k_adjf3<<<dim3(64, 448), 256, 0, stream>>>(cSt, out_adjf);
  } else {
    k_adjf<<<(ADJ_ELEMS / 4) / 256, 256, 0, stream>>>((const unsigned*)d_in[1], out_adjf);
  }

  if (mismatch >= 0) {
    float v = ldexpf(1024.f, mismatch);
    k_sentinel<<<1, 64, 0, stream>>>(out_node, v);
  }
}

// Round 4
// 609.905 us; speedup vs baseline: 1.0210x; 1.0210x over previous
//
#include <hip/hip_runtime.h>
#include <hip/hip_bf16.h>
#include <stdint.h>

static constexpr int B_  = 32;
static constexpr int E_  = 256;
static constexpr int N_  = 512;    // 2E
static constexpr int C_  = 256;    // H*F
static constexpr int BN  = B_ * N_;                      // 16384 = 2^14
static constexpr int NODE_ELEMS = B_ * N_ * C_;          // 4,194,304
static constexpr int ADJ_ELEMS  = B_ * 14 * N_ * N_;     // 117,440,512

// Adjacency planes (1 MB each, 448 total). Planes [0, SAFE_PLANE) overlap the
// scratch carved from the adj output region -> written by the final kernel.
// Planes [SAFE_PLANE, 448) are filled concurrently inside the compute kernels.
static constexpr int SAFE_PLANE = 56;
static constexpr int PL_G1 = 64;    // planes fused into gemm1
static constexpr int PL_A1 = 132;   // planes fused into attn1
static constexpr int PL_G2 = 64;    // planes fused into gemm2
static constexpr int PL_A2 = 132;   // planes fused into attn2  (56+64+132+64+132 = 448)

#define LOG2E 1.44269504088896340736f

typedef __attribute__((ext_vector_type(8))) short v8bf;
typedef __attribute__((ext_vector_type(4))) float v4f;

__device__ __forceinline__ unsigned short f2bfbits(float f) {
  union { float f; unsigned u; } x; x.f = f;
  unsigned u = x.u;
  return (unsigned short)((u + 0x7FFFu + ((u >> 16) & 1u)) >> 16);
}

// ---- shared adjacency stripe writer: one 256-thread block fills 8 rows of a plane ----
__device__ __forceinline__ void adj_fill_stripe(
    const int* __restrict__ st, float* __restrict__ adj, int plane, int stripe) {
  int r = plane % 14;
  int b = plane / 14;
  int i0 = stripe * 8;
  const int* stb = st + b * 255;
  size_t base = (size_t)plane * (512 * 512);
  #pragma unroll
  for (int itr = 0; itr < 4; ++itr) {
    int lin = itr * 256 + threadIdx.x;    // 0..1023 float4-chunks within 8 rows
    int i = i0 + (lin >> 7);
    int j0 = (lin & 127) << 2;
    float vals[4];
    #pragma unroll
    for (int q = 0; q < 4; ++q) {
      int j = j0 + q;
      int d = j - i;
      int ad = d < 0 ? -d : d;
      int mn = d < 0 ? j : i;
      int m4 = mn & 3;
      float v = 0.f;
      if (r == 13) {
        bool excl = (d == 0) || (ad == 2) || (ad == 3 && m4 == 0) || (ad == 1 && m4 == 3);
        v = excl ? 0.f : 1.f;
      } else if (r == 11) {
        v = (ad == 2 && (m4 == 0 || m4 == 3)) ? 1.f : 0.f;
      } else if (r == 12) {
        v = (ad == 2 && (m4 == 1 || m4 == 2)) ? 1.f : 0.f;
      } else {
        bool sp = (ad == 3 && m4 == 0) || (ad == 1 && m4 == 3);
        if (sp) v = (stb[mn >> 1] == r) ? 1.f : 0.f;
      }
      vals[q] = v;
    }
    v4f o = { vals[0], vals[1], vals[2], vals[3] };
    __builtin_nontemporal_store(o, (v4f*)&adj[base + (size_t)i * 512 + j0]);
  }
}

// ---------------- dtype-agnostic input conversion ----------------
// kind 0: float -> f32 ; kind 1: int -> i32 ; kind 2: float -> bf16 TRANSPOSED 256x256
struct ConvArgs {
  const void* src[15];
  void* dst[15];
  int n[15];
  int kind[15];
};

__global__ __launch_bounds__(256) void k_conv2(ConvArgs a, const unsigned* fprobe,
                                               const unsigned* iprobe) {
  __shared__ int fk_s, ik_s;
  int t = threadIdx.x;
  if (t == 0) {
    int c_even = 0, c_lo = 0;
    for (int k = 0; k < 32; ++k) {
      unsigned w = fprobe[2 * k];
      unsigned e32 = (w >> 23) & 0xFFu;
      unsigned elo = (w >> 7) & 0xFFu;
      if (e32 >= 105u && e32 <= 135u) ++c_even;
      if (elo >= 105u && elo <= 135u) ++c_lo;
    }
    fk_s = (c_even < 16) ? 2 : ((c_lo >= 16) ? 1 : 0);   // 2=f64, 1=bf16, 0=f32
    int hi0 = 0;
    for (int k = 0; k < 32; ++k) if (iprobe[2 * k + 1] == 0u) ++hi0;
    ik_s = (hi0 >= 30) ? 1 : 0;                          // 1=i64, 0=i32
  }
  __syncthreads();
  int fk = fk_s, ik = ik_s;
  int arr = blockIdx.y;
  int n = a.n[arr], kind = a.kind[arr];
  for (int idx = blockIdx.x * 256 + t; idx < n; idx += gridDim.x * 256) {
    if (kind == 1) {
      int v;
      if (ik == 1) v = (int)((const long long*)a.src[arr])[idx];
      else         v = ((const int*)a.src[arr])[idx];
      ((int*)a.dst[arr])[idx] = v;
    } else {
      float v;
      if (fk == 2) {
        v = (float)((const double*)a.src[arr])[idx];
      } else if (fk == 1) {
        unsigned short u = ((const unsigned short*)a.src[arr])[idx];
        union { unsigned u; float f; } c; c.u = (unsigned)u << 16; v = c.f;
      } else {
        v = ((const float*)a.src[arr])[idx];
      }
      if (kind == 0) {
        ((float*)a.dst[arr])[idx] = v;
      } else {           // kind 2: bf16, transposed [256][256]
        int kk = idx >> 8, cc = idx & 255;
        ((unsigned short*)a.dst[arr])[cc * 256 + kk] = f2bfbits(v);
      }
    }
  }
}

// ---------------- node features v4: 4 nodes per 256-thread block ----------------
__global__ __launch_bounds__(256) void k_feat4(
    const int* __restrict__ player, const float* __restrict__ Ax, const float* __restrict__ Ay,
    const float* __restrict__ Bx, const float* __restrict__ By,
    const float* __restrict__ emb, const float* __restrict__ Wc, const float* __restrict__ bc,
    const float* __restrict__ Wm, const float* __restrict__ bm, float* __restrict__ x) {
  int t = threadIdx.x, sub = t >> 6, lane = t & 63;
  int id = blockIdx.x * 4 + sub;        // b*512 + n
  int b = id >> 9, n = id & 511;
  int e = n >> 1, side = n & 1;
  __shared__ float feat[4][64];
  float v;
  if (lane < 32) {
    float cx = side ? Bx[b * E_ + e] : Ax[b * E_ + e];
    float cy = side ? By[b * E_ + e] : Ay[b * E_ + e];
    v = fmaxf(fmaf(cx, Wc[lane], fmaf(cy, Wc[32 + lane], bc[lane])), 0.f);
  } else {
    int pid = player[b * 2 + side];
    v = emb[pid * 32 + (lane - 32)];
  }
  feat[sub][lane] = v;
  __syncthreads();
  float acc = bm[lane];
  #pragma unroll 8
  for (int c = 0; c < 64; ++c) acc = fmaf(feat[sub][c], Wm[c * 64 + lane], acc);
  x[(size_t)id * 64 + lane] = acc;
}

// ---------------- layer-1 tiled GEMM (f32) + fused GAT score epilogue + fused adj ----------------
// Writes h as bf16 TRANSPOSED hbT[f * 16384 + row]  (attn B-operand layout).
__global__ __launch_bounds__(256) void k_gemm(
    const float* __restrict__ x, const float* __restrict__ W, unsigned short* __restrict__ hbT,
    int K, const float* __restrict__ att, float* __restrict__ ssO, float* __restrict__ sdO,
    const int* __restrict__ adj_st, float* __restrict__ adj_out, int adj_plane0) {
  int blk = blockIdx.x;
  if (blk >= 1024) {                      // fused adjacency blocks
    if (adj_st) {
      int ab = blk - 1024;
      adj_fill_stripe(adj_st, adj_out, adj_plane0 + (ab >> 6), ab & 63);
    }
    return;
  }
  __shared__ float xs[64 * 64];
  __shared__ float wt[64 * 64];
  int row0 = (blk & 255) * 64;
  int hd = blk >> 8;
  int col0 = hd * 64;
  int t = threadIdx.x;
  int tx = t & 15, ty = t >> 4;
  float acc[4][4] = {};
  for (int kt = 0; kt < K; kt += 64) {
    #pragma unroll
    for (int q = 0; q < 4; ++q) {
      int v = q * 256 + t;            // float4 chunk id 0..1023
      int r = v >> 4, c = (v & 15) * 4;
      *(float4*)&xs[r * 64 + c] = *(const float4*)&x[(size_t)(row0 + r) * K + kt + c];
      *(float4*)&wt[r * 64 + c] = *(const float4*)&W[(size_t)(kt + r) * C_ + col0 + c];
    }
    __syncthreads();
    #pragma unroll 4
    for (int k = 0; k < 64; ++k) {
      float xv[4];
      #pragma unroll
      for (int r = 0; r < 4; ++r) xv[r] = xs[(ty * 4 + r) * 64 + k];
      float4 wf = *(const float4*)&wt[k * 64 + tx * 4];
      #pragma unroll
      for (int r = 0; r < 4; ++r) {
        acc[r][0] = fmaf(xv[r], wf.x, acc[r][0]);
        acc[r][1] = fmaf(xv[r], wf.y, acc[r][1]);
        acc[r][2] = fmaf(xv[r], wf.z, acc[r][2]);
        acc[r][3] = fmaf(xv[r], wf.w, acc[r][3]);
      }
    }
    __syncthreads();
  }
  // bf16 transposed store: for fixed col c, acc[0..3][c] are 4 consecutive rows.
  #pragma unroll
  for (int c = 0; c < 4; ++c) {
    unsigned f = (unsigned)(col0 + tx * 4 + c);
    ushort4 o;
    o.x = f2bfbits(acc[0][c]); o.y = f2bfbits(acc[1][c]);
    o.z = f2bfbits(acc[2][c]); o.w = f2bfbits(acc[3][c]);
    *(ushort4*)&hbT[(f << 14) + row0 + ty * 4] = o;
  }
  float attS[4], attD[4];
  #pragma unroll
  for (int c = 0; c < 4; ++c) {
    attS[c] = att[hd * 128 + tx * 4 + c];
    attD[c] = att[hd * 128 + 64 + tx * 4 + c];
  }
  #pragma unroll
  for (int r = 0; r < 4; ++r) {
    float p1 = acc[r][0] * attS[0] + acc[r][1] * attS[1] + acc[r][2] * attS[2] + acc[r][3] * attS[3];
    float p2 = acc[r][0] * attD[0] + acc[r][1] * attD[1] + acc[r][2] * attD[2] + acc[r][3] * attD[3];
    #pragma unroll
    for (int d = 8; d > 0; d >>= 1) {
      p1 += __shfl_xor(p1, d, 16);
      p2 += __shfl_xor(p2, d, 16);
    }
    if (tx == 0) {
      int row = row0 + ty * 4 + r;
      int bb = row >> 9, nn = row & 511;
      int idx = (bb * 4 + hd) * N_ + nn;
      ssO[idx] = p1; sdO[idx] = p2;
    }
  }
}

// ---------------- layer-2 MFMA GEMM (bf16 in) + fused score epilogue + fused adj ----------------
// Writes h as bf16 TRANSPOSED hbT[f * 16384 + row].
__global__ __launch_bounds__(256) void k_gemm2_mfma(
    const unsigned short* __restrict__ xb, const unsigned short* __restrict__ wt,
    unsigned short* __restrict__ hbT, const float* __restrict__ att,
    float* __restrict__ ssO, float* __restrict__ sdO,
    const int* __restrict__ adj_st, float* __restrict__ adj_out, int adj_plane0) {
  int blk = blockIdx.x;
  if (blk >= 1024) {                      // fused adjacency blocks
    if (adj_st) {
      int ab = blk - 1024;
      adj_fill_stripe(adj_st, adj_out, adj_plane0 + (ab >> 6), ab & 63);
    }
    return;
  }
  int row0 = (blk & 255) * 64;
  int hd = blk >> 8;
  int col0 = hd * 64;
  int t = threadIdx.x, w = t >> 6, l = t & 63;
  int lane16 = l & 15, quad = l >> 4;
  int arow = row0 + w * 16 + lane16;        // A m-row
  v4f acc[4] = {};
  #pragma unroll
  for (int ks = 0; ks < 8; ++ks) {
    int kb = ks * 32 + quad * 8;
    v8bf a = *(const v8bf*)&xb[(size_t)arow * 256 + kb];
    #pragma unroll
    for (int fs = 0; fs < 4; ++fs) {
      v8bf b = *(const v8bf*)&wt[(size_t)(col0 + fs * 16 + lane16) * 256 + kb];
      acc[fs] = __builtin_amdgcn_mfma_f32_16x16x32_bf16(a, b, acc[fs], 0, 0, 0);
    }
  }
  // bf16 transposed store: acc[fs][0..3] = rows quad*4+0..3 (consecutive), col fixed.
  #pragma unroll
  for (int fs = 0; fs < 4; ++fs) {
    unsigned f = (unsigned)(col0 + fs * 16 + lane16);
    ushort4 o;
    o.x = f2bfbits(acc[fs][0]); o.y = f2bfbits(acc[fs][1]);
    o.z = f2bfbits(acc[fs][2]); o.w = f2bfbits(acc[fs][3]);
    *(ushort4*)&hbT[(f << 14) + row0 + w * 16 + quad * 4] = o;
  }
  float attS[4], attD[4];
  #pragma unroll
  for (int fs = 0; fs < 4; ++fs) {
    attS[fs] = att[hd * 128 + fs * 16 + lane16];
    attD[fs] = att[hd * 128 + 64 + fs * 16 + lane16];
  }
  #pragma unroll
  for (int r = 0; r < 4; ++r) {
    int row = row0 + w * 16 + quad * 4 + r;
    float p1 = acc[0][r] * attS[0] + acc[1][r] * attS[1] + acc[2][r] * attS[2] + acc[3][r] * attS[3];
    float p2 = acc[0][r] * attD[0] + acc[1][r] * attD[1] + acc[2][r] * attD[2] + acc[3][r] * attD[3];
    #pragma unroll
    for (int d = 8; d > 0; d >>= 1) {
      p1 += __shfl_xor(p1, d, 16);
      p2 += __shfl_xor(p2, d, 16);
    }
    if (lane16 == 0) {
      int bb = row >> 9, nn = row & 511;
      int idx = (bb * 4 + hd) * N_ + nn;
      ssO[idx] = p1; sdO[idx] = p2;
    }
  }
}

// ---------------- MFMA attention v4 + fused adj ----------------
// No LDS h-staging, no in-loop barriers. RELU=1: bf16 out (relu); RELU=0: f32 NT out.
template <int RELU>
__global__ __launch_bounds__(256) void k_attn_mfma4(
    const unsigned short* __restrict__ hbT, const float* __restrict__ ss,
    const float* __restrict__ sd, void* __restrict__ outp,
    const int* __restrict__ adj_st, float* __restrict__ adj_out, int adj_plane0) {
  int blk = blockIdx.x;
  if (blk >= 1024) {                      // fused adjacency blocks
    if (adj_st) {
      int ab = blk - 1024;
      adj_fill_stripe(adj_st, adj_out, adj_plane0 + (ab >> 6), ab & 63);
    }
    return;
  }
  __shared__ float sdl[512];
  __shared__ float red[4];
  int it = blk & 7, hd = (blk >> 3) & 3, b = blk >> 5;
  int i0 = it * 64, bh = b * 4 + hd;
  int t = threadIdx.x, w = t >> 6, l = t & 63;
  int lane16 = l & 15, quad = l >> 4;
  float v0 = sd[(size_t)bh * N_ + t];
  float v1 = sd[(size_t)bh * N_ + 256 + t];
  sdl[t] = v0; sdl[256 + t] = v1;
  float mx = fmaxf(v0, v1);
  #pragma unroll
  for (int d = 32; d > 0; d >>= 1) mx = fmaxf(mx, __shfl_xor(mx, d, 64));
  if (l == 0) red[w] = mx;
  __syncthreads();
  mx = fmaxf(fmaxf(red[0], red[1]), fmaxf(red[2], red[3]));
  int iw = i0 + w * 16 + lane16;           // this lane's i
  float ss_s = ss[(size_t)bh * N_ + iw];
  float sv0 = ss_s + mx;
  float m2_s = fmaxf(sv0, 0.2f * sv0) * LOG2E;  // leaky monotone -> row-max bound
  float lsum = 0.f;
  v4f acc[4] = {};
  const unsigned short* hb = hbT + ((unsigned)(hd * 64) << 14) + b * 512;
  for (int jt = 0; jt < 8; ++jt) {
    int j0 = jt * 64;
    #pragma unroll
    for (int ks = 0; ks < 2; ++ks) {
      int kb = ks * 32 + quad * 8;
      v8bf afr;
      #pragma unroll
      for (int q = 0; q < 8; ++q) {
        int j = j0 + kb + q;
        float sv = ss_s + sdl[j];
        float sc = fmaxf(sv, 0.2f * sv);
        float p = exp2f(fmaf(sc, LOG2E, -m2_s));
        if (iw == j) p = 0.f;
        lsum += p;
        afr[q] = (short)f2bfbits(p);
      }
      #pragma unroll
      for (int fs = 0; fs < 4; ++fs) {
        v8bf bfr = *(const v8bf*)&hb[((unsigned)(fs * 16 + lane16) << 14) + j0 + kb];
        acc[fs] = __builtin_amdgcn_mfma_f32_16x16x32_bf16(afr, bfr, acc[fs], 0, 0, 0);
      }
    }
  }
  // cross-quad reduce of row sums; after this every quad holds row lane16's sum.
  lsum += __shfl_xor(lsum, 16, 64);
  lsum += __shfl_xor(lsum, 32, 64);
  // epilogue: C/D layout col = lane16 (f), row = quad*4 + reg (i)
  #pragma unroll
  for (int r = 0; r < 4; ++r) {
    int i = i0 + w * 16 + quad * 4 + r;
    float scale = 1.f / __shfl(lsum, quad * 4 + r, 16);
    #pragma unroll
    for (int fs = 0; fs < 4; ++fs) {
      int f = fs * 16 + lane16;
      float vv = acc[fs][r] * scale;
      size_t o = (size_t)(b * N_ + i) * C_ + hd * 64 + f;
      if constexpr (RELU) {
        ((unsigned short*)outp)[o] = f2bfbits(fmaxf(vv, 0.f));
      } else {
        __builtin_nontemporal_store(vv, &((float*)outp)[o]);
      }
    }
  }
}

// ---------------- adjacency tail: planes [0, SAFE_PLANE) after scratch is dead ----------------
__global__ __launch_bounds__(256) void k_adjf3(
    const int* __restrict__ st, float* __restrict__ adj) {
  adj_fill_stripe(st, adj, blockIdx.y, blockIdx.x);
}

// ---------------- adjacency fallback: raw input + per-block sniff ----------------
__global__ __launch_bounds__(256) void k_adjf(
    const unsigned* __restrict__ st_raw, float* __restrict__ adj) {
  __shared__ int i64_s;
  if (threadIdx.x == 0) {
    int hi0 = 0;
    for (int k = 0; k < 32; ++k) if (st_raw[2 * k + 1] == 0u) ++hi0;
    i64_s = (hi0 >= 30) ? 1 : 0;
  }
  __syncthreads();
  int is64 = i64_s;
  int chunk = blockIdx.x * 256 + threadIdx.x;
  int j0 = (chunk & 127) << 2;
  int rowid = chunk >> 7;
  int i = rowid & 511;
  int plane = rowid >> 9;
  int r = plane % 14;
  int b = plane / 14;
  float vals[4];
  #pragma unroll
  for (int q = 0; q < 4; ++q) {
    int j = j0 + q;
    int d = j - i;
    int ad = d < 0 ? -d : d;
    int mn = d < 0 ? j : i;
    int m4 = mn & 3;
    float v = 0.f;
    if (r == 13) {
      bool excl = (d == 0) || (ad == 2) || (ad == 3 && m4 == 0) || (ad == 1 && m4 == 3);
      v = excl ? 0.f : 1.f;
    } else if (r == 11) {
      v = (ad == 2 && (m4 == 0 || m4 == 3)) ? 1.f : 0.f;
    } else if (r == 12) {
      v = (ad == 2 && (m4 == 1 || m4 == 2)) ? 1.f : 0.f;
    } else {
      bool sp = (ad == 3 && m4 == 0) || (ad == 1 && m4 == 3);
      if (sp) {
        int e = b * 255 + (mn >> 1);
        int stv = is64 ? (int)st_raw[2 * e] : (int)st_raw[e];
        v = (stv == r) ? 1.f : 0.f;
      }
    }
    vals[q] = v;
  }
  *(float4*)&adj[(size_t)chunk * 4] = make_float4(vals[0], vals[1], vals[2], vals[3]);
}

// ---------------- sentinel ----------------
__global__ void k_sentinel(float* out, float v) {
  if (threadIdx.x == 0 && blockIdx.x == 0) out[0] = v;
}

extern "C" void kernel_launch(void* const* d_in, const int* in_sizes, int n_in,
                              void* d_out, int out_size, void* d_ws, size_t ws_size,
                              hipStream_t stream) {
  static const int expA[16] = {64,8160,8192,8192,8192,8192,1,1120,64,32,4096,64,16384,512,65536,512};
  static const int expB[15] = {64,8160,8192,8192,8192,8192,1120,64,32,4096,64,16384,512,65536,512};
  int mismatch = -1;
  int base = 7;
  if (n_in == 16) {
    base = 7;
    for (int i = 0; i < 16; ++i) if (in_sizes[i] != expA[i]) { mismatch = i; break; }
  } else if (n_in == 15) {
    base = 6;
    for (int i = 0; i < 15; ++i) if (in_sizes[i] != expB[i]) { mismatch = i; break; }
  } else {
    mismatch = 17;
  }
  if (mismatch < 0 && out_size != NODE_ELEMS + ADJ_ELEMS) mismatch = 16;

  float* out_node = (float*)d_out;                 // f32 output
  float* out_adjf = out_node + NODE_ELEMS;

  // Scratch carved from the f32 adj output region (470 MB); planes < SAFE_PLANE
  // overlap scratch and are written by the tail kernel only.
  char* scr = (char*)out_adjf;
  float* x  = (float*)(scr);                       //  4 MB
  unsigned short* hbT = (unsigned short*)(scr + (size_t)( 4u << 20)); // 8 MB bf16 h^T [f][row]
  unsigned short* x2b = (unsigned short*)(scr + (size_t)(24u << 20)); // 8 MB bf16
  float* ss = (float*)(scr + (size_t)(44u << 20)); // 256 KB
  float* sd = (float*)(scr + (size_t)(45u << 20)); // 256 KB
  float* cv = (float*)(scr + (size_t)(48u << 20)); // converted inputs (ends < 49 MB)

  float* cAx  = cv + 0;
  float* cAy  = cv + 8192;
  float* cBx  = cv + 16384;
  float* cBy  = cv + 24576;
  float* cEmb = cv + 32768;
  float* cWc  = cv + 33888;
  float* cbc  = cv + 33952;
  float* cWm  = cv + 33984;
  float* cbm  = cv + 38080;
  float* cW1  = cv + 38144;
  float* cA1  = cv + 54528;
  unsigned short* cW2T = (unsigned short*)(cv + 55040);  // 128 KB bf16 transposed
  float* cA2  = cv + 120576;
  int*   cPl  = (int*)(cv + 121088);

  bool ws_ok = (ws_size >= 8160 * sizeof(int));
  int* cSt = ws_ok ? (int*)d_ws : nullptr;

  ConvArgs a;
  a.src[0]  = d_in[2];        a.dst[0]  = cAx;  a.n[0]  = 8192;  a.kind[0]  = 0;
  a.src[1]  = d_in[3];        a.dst[1]  = cAy;  a.n[1]  = 8192;  a.kind[1]  = 0;
  a.src[2]  = d_in[4];        a.dst[2]  = cBx;  a.n[2]  = 8192;  a.kind[2]  = 0;
  a.src[3]  = d_in[5];        a.dst[3]  = cBy;  a.n[3]  = 8192;  a.kind[3]  = 0;
  a.src[4]  = d_in[base + 0]; a.dst[4]  = cEmb; a.n[4]  = 1120;  a.kind[4]  = 0;
  a.src[5]  = d_in[base + 1]; a.dst[5]  = cWc;  a.n[5]  = 64;    a.kind[5]  = 0;
  a.src[6]  = d_in[base + 2]; a.dst[6]  = cbc;  a.n[6]  = 32;    a.kind[6]  = 0;
  a.src[7]  = d_in[base + 3]; a.dst[7]  = cWm;  a.n[7]  = 4096;  a.kind[7]  = 0;
  a.src[8]  = d_in[base + 4]; a.dst[8]  = cbm;  a.n[8]  = 64;    a.kind[8]  = 0;
  a.src[9]  = d_in[base + 5]; a.dst[9]  = cW1;  a.n[9]  = 16384; a.kind[9]  = 0;
  a.src[10] = d_in[base + 6]; a.dst[10] = cA1;  a.n[10] = 512;   a.kind[10] = 0;
  a.src[11] = d_in[base + 7]; a.dst[11] = cW2T; a.n[11] = 65536; a.kind[11] = 2;
  a.src[12] = d_in[base + 8]; a.dst[12] = cA2;  a.n[12] = 512;   a.kind[12] = 0;
  a.src[13] = d_in[0];        a.dst[13] = cPl;  a.n[13] = 64;    a.kind[13] = 1;
  a.src[14] = d_in[1];        a.dst[14] = ws_ok ? (void*)cSt : (void*)cPl;
  a.n[14] = ws_ok ? 8160 : 0; a.kind[14] = 1;

  k_conv2<<<dim3(64, 15), 256, 0, stream>>>(a, (const unsigned*)d_in[base + 3],
                                            (const unsigned*)d_in[0]);

  k_feat4<<<BN / 4, 256, 0, stream>>>(cPl, cAx, cAy, cBx, cBy, cEmb, cWc, cbc, cWm, cbm, x);

  // Fused-adj plane bases (planes SAFE_PLANE..448 distributed over the 4 big kernels).
  int p_g1 = SAFE_PLANE;               // 56
  int p_a1 = p_g1 + PL_G1;             // 120
  int p_g2 = p_a1 + PL_A1;             // 252
  int p_a2 = p_g2 + PL_G2;             // 316  (+132 = 448)

  // ---- layer 1 ----
  k_gemm<<<1024 + PL_G1 * 64, 256, 0, stream>>>(x, cW1, hbT, 64, cA1, ss, sd,
                                                cSt, out_adjf, p_g1);
  k_attn_mfma4<1><<<1024 + PL_A1 * 64, 256, 0, stream>>>(hbT, ss, sd, x2b,
                                                         cSt, out_adjf, p_a1);

  // ---- layer 2 ----
  k_gemm2_mfma<<<1024 + PL_G2 * 64, 256, 0, stream>>>(x2b, cW2T, hbT, cA2, ss, sd,
                                                      cSt, out_adjf, p_g2);
  k_attn_mfma4<0><<<1024 + PL_A2 * 64, 256, 0, stream>>>(hbT, ss, sd, out_node,
                                                         cSt, out_adjf, p_a2);

  // ---- adjacency tail: planes overlapping scratch, written after scratch is dead ----
  if (ws_ok) {
    k_adjf3<<<dim3(64, SAFE_PLANE), 256, 0, stream>>>(cSt, out_adjf);
  } else {
    k_adjf<<<(ADJ_ELEMS / 4) / 256, 256, 0, stream>>>((const unsigned*)d_in[1], out_adjf);
  }

  if (mismatch >= 0) {
    float v = ldexpf(1024.f, mismatch);
    k_sentinel<<<1, 64, 0, stream>>>(out_node, v);
  }
}